// Round 1
// baseline (597.327 us; speedup 1.0000x reference)
//
#include <hip/hip_runtime.h>
#include <cstddef>

// SkipGRU on MI355X (gfx950) — round 6.
// = round 5 structure (64n x 192c tile, BK=32, XCD swizzle, readfirstlane
//   wave id, coalesced pack_x) + counted-vmcnt deep pipeline in gru_step:
//   4 x 16KB LDS buffers, stage 3 K-chunks ahead, s_waitcnt vmcnt(8) + raw
//   s_barrier per kt (never drain to 0 in the main loop), setprio(1) around
//   the MFMA cluster. This removes the per-kt vmcnt(0) drain that
//   __syncthreads() forced (the m97-structure ~20%+ stall).
//
// Layouts (unchanged):
//  xb[t][nb(64)][kt(16)][g(4)][row(64)][8] bf16 granules (16B).
//  Bt[cc(24)][kt(32)][g(4)][col(64)][8]    (cc = 64 gemm-cols).
//  h ping-pong: same granule layout as xb per nb.

typedef unsigned short u16;
typedef __attribute__((ext_vector_type(8))) short short8;
typedef __attribute__((ext_vector_type(8))) u16 u16x8;
typedef __attribute__((ext_vector_type(4))) float floatx4;

#define MFMA16(a, b, c) __builtin_amdgcn_mfma_f32_16x16x32_bf16((a), (b), (c), 0, 0, 0)

__device__ __forceinline__ u16 f32_to_bf16(float f) {
  union { float f; unsigned int u; } c; c.f = f;
  unsigned int u = c.u + 0x7FFFu + ((c.u >> 16) & 1u);  // RNE
  return (u16)(u >> 16);
}
__device__ __forceinline__ float bf16_to_f32(u16 v) {
  union { unsigned int u; float f; } c; c.u = ((unsigned int)v) << 16;
  return c.f;
}
__device__ __forceinline__ float sigmoidf_(float x) {
  return 1.0f / (1.0f + __expf(-x));
}
__device__ __forceinline__ void gload_lds16(const void* g, void* l) {
  __builtin_amdgcn_global_load_lds(
      (const __attribute__((address_space(1))) unsigned int*)g,
      (__attribute__((address_space(3))) unsigned int*)l, 16, 0, 0);
}

// ---------------------------------------------------------------------------
// pack_x: coalesced. Block = one (t, nb): 64 rows x 512 c.
// Phase A: read x rows coalesced (f32x8/thread), convert, store granules into
// LDS at XOR-swizzled column; Phase B: write granules [kt][g][row][8] coalesced.
// ---------------------------------------------------------------------------
__global__ __launch_bounds__(256)
void pack_x(const float* __restrict__ x, u16* __restrict__ xb) {
  __shared__ u16 sm[64 * 512];              // 64KB
  const int t = blockIdx.x >> 6;
  const int nb = blockIdx.x & 63;
  const int tid = threadIdx.x;
#pragma unroll
  for (int it = 0; it < 16; ++it) {
    int idx = it * 256 + tid;
    int row = idx >> 6, ch = idx & 63;      // row 0..63, ch = 8-float chunk
    int xrow = (nb * 2 + (row >> 5)) * 512 + t * 32 + (row & 31);
    const float* src = x + (size_t)xrow * 512 + ch * 8;
    floatx4 va = *(const floatx4*)src;
    floatx4 vb = *(const floatx4*)(src + 4);
    u16x8 pk;
    pk[0] = f32_to_bf16(va[0]); pk[1] = f32_to_bf16(va[1]);
    pk[2] = f32_to_bf16(va[2]); pk[3] = f32_to_bf16(va[3]);
    pk[4] = f32_to_bf16(vb[0]); pk[5] = f32_to_bf16(vb[1]);
    pk[6] = f32_to_bf16(vb[2]); pk[7] = f32_to_bf16(vb[3]);
    *(u16x8*)&sm[row * 512 + (ch ^ (row & 7)) * 8] = pk;
  }
  __syncthreads();
  u16* dst = xb + (size_t)blockIdx.x * 32768;   // blockIdx = t*64+nb = layout order
#pragma unroll
  for (int it = 0; it < 16; ++it) {
    int idx = it * 256 + tid;
    int row = idx & 63, g = (idx >> 6) & 3, kt = idx >> 8;
    int ch = kt * 4 + g;
    u16x8 vv = *(const u16x8*)&sm[row * 512 + (ch ^ (row & 7)) * 8];
    *(u16x8*)(dst + (size_t)idx * 8) = vv;
  }
}

// ---------------------------------------------------------------------------
// pack_Bt: [W;U] -> Bt bf16 [cc(24)][kt(32)][g(4)][col(64)][8]
// ---------------------------------------------------------------------------
__global__ void pack_Bt(const float* __restrict__ W, const float* __restrict__ U,
                        u16* __restrict__ Bt) {
  size_t gid = (size_t)blockIdx.x * 256 + threadIdx.x;   // < 196608
  int col = (int)(gid & 63);
  int g   = (int)((gid >> 6) & 3);
  int kt  = (int)((gid >> 8) & 31);
  int cc  = (int)(gid >> 13);
  int c = cc * 64 + col;
  int k0 = kt * 32 + g * 8;
  u16x8 pk;
#pragma unroll
  for (int j = 0; j < 8; ++j) {
    int k = k0 + j;
    float v = (k < 512) ? W[(size_t)k * 1536 + c] : U[(size_t)(k - 512) * 1536 + c];
    pk[j] = f32_to_bf16(v);
  }
  *(u16x8*)(Bt + gid * 8) = pk;
}

// ---------------------------------------------------------------------------
// gru_step: one GRU timestep.
// Grid 512 linear, XCD-swizzled: nb = (idx>>6)*8 + (idx&7), hb = (idx>>3)&7
// (all 8 hb-blocks of an nb land on one XCD; per-XCD set = 1MB A/h + 3MB B).
// Block tile 64n x 192c; 4 waves (wy,wx); wave = 32n x (3 gates x 32 h-cols).
// LDS: 4 x 16KB ring (A 4KB [g4][row64][16B] + B 3 x 4KB [g4][col64][16B]).
// K-loop: counted-vmcnt pipeline, 3 stages in flight, one s_barrier per kt.
// ---------------------------------------------------------------------------
__global__ __launch_bounds__(256)
void gru_step(const u16* __restrict__ xb, const u16* __restrict__ Bt,
              const float* __restrict__ bias,
              const u16* __restrict__ h_in, u16* __restrict__ h_out,
              float* __restrict__ out, int t, int first, int last) {
  __shared__ alignas(16) char sm[65536];    // 4 x 16KB ring -> 2 blocks/CU
  const int tid = threadIdx.x;
  const int idx = blockIdx.x;
  const int nb = ((idx >> 6) << 3) | (idx & 7);   // 0..63
  const int hb = (idx >> 3) & 7;                  // 0..7
  // WAVE-UNIFORM wave id: forces SGPR so global_load_lds LDS destinations are
  // provably uniform (no compiler waterfall around each load).
  const int w = __builtin_amdgcn_readfirstlane(tid >> 6);
  const int lane = tid & 63;
  const int wy = w >> 1, wx = w & 1;              // scalar
  const int q = lane >> 4, lc = lane & 15;

  const u16* xbB = xb + (size_t)(t * 64 + nb) * 32768;
  const u16* htB = h_in + (size_t)nb * 32768;
  const int cs0 = hb, cs1 = 8 + hb, cs2 = 16 + hb;   // z / r / h-gate col-chunks

  floatx4 acZ[2][2] = {{{0.f,0.f,0.f,0.f},{0.f,0.f,0.f,0.f}},{{0.f,0.f,0.f,0.f},{0.f,0.f,0.f,0.f}}};
  floatx4 acR[2][2] = {{{0.f,0.f,0.f,0.f},{0.f,0.f,0.f,0.f}},{{0.f,0.f,0.f,0.f},{0.f,0.f,0.f,0.f}}};
  floatx4 acX[2][2] = {{{0.f,0.f,0.f,0.f},{0.f,0.f,0.f,0.f}},{{0.f,0.f,0.f,0.f},{0.f,0.f,0.f,0.f}}};
  floatx4 acH[2][2] = {{{0.f,0.f,0.f,0.f},{0.f,0.f,0.f,0.f}},{{0.f,0.f,0.f,0.f},{0.f,0.f,0.f,0.f}}};

  const int ktall = first ? 16 : 32;
  const int wo = w * 1024;   // SGPR: per-wave byte slot within each 4KB panel

  // Stage K-chunk kt (A 4KB + 3 gate-B 4KB) into ring slot bsel. 4 glds16/wave.
  auto stage = [&](int kt, int bsel) {
    char* lds = sm + bsel * 16384;            // bsel scalar -> uniform base
    const char* aS = (const char*)((kt < 16) ? (xbB + (size_t)kt * 2048)
                                             : (htB + (size_t)(kt - 16) * 2048));
    gload_lds16(aS + wo + lane * 16, lds + wo);
    gload_lds16((const char*)(Bt + (size_t)(cs0 * 32 + kt) * 2048) + wo + lane * 16,
                lds + 4096 + wo);
    gload_lds16((const char*)(Bt + (size_t)(cs1 * 32 + kt) * 2048) + wo + lane * 16,
                lds + 8192 + wo);
    gload_lds16((const char*)(Bt + (size_t)(cs2 * 32 + kt) * 2048) + wo + lane * 16,
                lds + 12288 + wo);
  };

  // Compute one K-chunk from ring slot bsel; third-gate acc is acX (x@W) / acH.
  auto compute = [&](int bsel, floatx4 (&acT)[2][2]) {
    const char* lds = sm + bsel * 16384;
    short8 a0 = *(const short8*)(lds + (q * 64 + wy * 32 + lc) * 16);
    short8 a1 = *(const short8*)(lds + (q * 64 + wy * 32 + 16 + lc) * 16);
#pragma unroll
    for (int ci = 0; ci < 2; ++ci) {
      int co = (q * 64 + wx * 32 + ci * 16 + lc) * 16;
      short8 bz = *(const short8*)(lds + 4096 + co);
      short8 br = *(const short8*)(lds + 8192 + co);
      short8 bh = *(const short8*)(lds + 12288 + co);
      acZ[0][ci] = MFMA16(a0, bz, acZ[0][ci]);
      acZ[1][ci] = MFMA16(a1, bz, acZ[1][ci]);
      acR[0][ci] = MFMA16(a0, br, acR[0][ci]);
      acR[1][ci] = MFMA16(a1, br, acR[1][ci]);
      acT[0][ci] = MFMA16(a0, bh, acT[0][ci]);
      acT[1][ci] = MFMA16(a1, bh, acT[1][ci]);
    }
  };

  // ---- Pipelined K-loop: 3 stages in flight, counted vmcnt, 1 barrier/kt.
  // vmcnt invariant at iter kt: issued stages = kt..min(kt+2,ktall-1);
  // waiting vmcnt(4*(#stages issued after kt)) guarantees own stage(kt)
  // landed (vmcnt completes in issue order); barrier then publishes all
  // waves' stage(kt). stage(kt+3) overwrites buf[(kt-1)&3], which every
  // wave finished reading before this barrier (all ds_read results are
  // consumed by MFMAs inside compute(kt-1), i.e. pre-barrier).
  stage(0, 0);
  stage(1, 1);
  stage(2, 2);
  int kt = 0;
  for (; kt < ktall - 2; ++kt) {
    asm volatile("s_waitcnt vmcnt(8)" ::: "memory");
    __builtin_amdgcn_s_barrier();
    if (kt + 3 < ktall) stage(kt + 3, (kt + 3) & 3);
    __builtin_amdgcn_s_setprio(1);
    compute(kt & 3, (kt < 16) ? acX : acH);
    __builtin_amdgcn_s_setprio(0);
  }
  // kt = ktall-2: only stage(kt+1) still in flight after own stage(kt) lands.
  asm volatile("s_waitcnt vmcnt(4)" ::: "memory");
  __builtin_amdgcn_s_barrier();
  __builtin_amdgcn_s_setprio(1);
  compute(kt & 3, (kt < 16) ? acX : acH);
  __builtin_amdgcn_s_setprio(0);
  ++kt;
  // kt = ktall-1: final chunk, drain.
  asm volatile("s_waitcnt vmcnt(0)" ::: "memory");
  __builtin_amdgcn_s_barrier();
  __builtin_amdgcn_s_setprio(1);
  compute(kt & 3, (kt < 16) ? acX : acH);
  __builtin_amdgcn_s_setprio(0);

  // ---- Epilogue. C/D layout: col = lane&15, row = quad*4 + reg ----
  // Safety barrier before reusing sm as Ct (also drains any stragglers).
  __syncthreads();
  const float* b0 = bias;
  const float* b1 = bias + 1536;
  u16* Ct = (u16*)sm;    // 64 rows x 72 u16 (9KB)
#pragma unroll
  for (int ci = 0; ci < 2; ++ci) {
    const int hcl = wx * 32 + ci * 16 + lc;    // 0..63
    const int hg = hb * 64 + hcl;              // 0..511
    const float bz = b0[hg] + b1[hg];
    const float br = b0[512 + hg] + b1[512 + hg];
    const float b0h = b0[1024 + hg];
    const float b1h = b1[1024 + hg];
    const int ktg = hg >> 5;
    const int gg = (hg >> 3) & 3;
    const size_t hbase = (((size_t)nb * 16 + ktg) * 4 + gg) * 64;
#pragma unroll
    for (int mi = 0; mi < 2; ++mi) {
#pragma unroll
      for (int reg = 0; reg < 4; ++reg) {
        const int nl = wy * 32 + mi * 16 + q * 4 + reg;   // 0..63
        const int n = nb * 64 + nl;
        float z = sigmoidf_(acZ[mi][ci][reg] + bz);
        float r = sigmoidf_(acR[mi][ci][reg] + br);
        float hh = acX[mi][ci][reg] + b0h + r * (acH[mi][ci][reg] + b1h);
        hh = fmaxf(hh, 0.0f);
        float hp = 0.0f;
        if (!first) hp = bf16_to_f32(h_in[(hbase + nl) * 8 + (hg & 7)]);
        float v = z * hp + (1.0f - z) * hh;
        if (last) out[(size_t)n * 512 + hg] = v;
        else      Ct[nl * 72 + hcl] = f32_to_bf16(v);
      }
    }
  }
  if (!last) {
    __syncthreads();
    // Re-emit h in granule layout: 512 granules (row64 x g4 x ktl2), 2/thread.
#pragma unroll
    for (int i = 0; i < 2; ++i) {
      int e = i * 256 + tid;
      int row = e & 63;
      int g = (e >> 6) & 3;
      int ktl = e >> 8;                         // 0..1
      u16x8 vv = *(const u16x8*)(Ct + row * 72 + ktl * 32 + g * 8);
      *(u16x8*)(h_out + ((((size_t)nb * 16 + (hb * 2 + ktl)) * 4 + g) * 64 + row) * 8) = vv;
    }
  }
}

// ---------------------------------------------------------------------------
extern "C" void kernel_launch(void* const* d_in, const int* in_sizes, int n_in,
                              void* d_out, int out_size, void* d_ws, size_t ws_size,
                              hipStream_t stream) {
  const float* x = (const float*)d_in[0];    // (128,512,512)
  const float* W = (const float*)d_in[1];    // (512,1536)
  const float* U = (const float*)d_in[2];    // (512,1536)
  const float* bias = (const float*)d_in[3]; // (2,1536)
  float* out = (float*)d_out;                // (128,16384)

  u16* xb = (u16*)d_ws;                      // 16*64*32768 u16 = 64 MB
  u16* Bt = xb + (size_t)16 * 64 * 32768;    // 3 MB
  u16* h0 = Bt + (size_t)1536 * 1024;        // 4 MB
  u16* h1 = h0 + (size_t)4096 * 512;         // 4 MB

  pack_x<<<1024, 256, 0, stream>>>(x, xb);
  pack_Bt<<<768, 256, 0, stream>>>(W, U, Bt);

  for (int t = 0; t < 16; ++t) {
    const u16* hin = (t & 1) ? h1 : h0;      // t=0 never reads h
    u16* hout = (t & 1) ? h0 : h1;
    gru_step<<<512, 256, 0, stream>>>(
        xb, Bt, bias, hin, hout, out, t, (t == 0) ? 1 : 0, (t == 15) ? 1 : 0);
  }
}

// Round 2
// 503.626 us; speedup vs baseline: 1.1861x; 1.1861x over previous
//
#include <hip/hip_runtime.h>
#include <cstddef>

// SkipGRU on MI355X (gfx950) — round 7.
// = round 6 (4 x 16KB LDS ring, 3-ahead counted-vmcnt pipeline, raw s_barrier,
//   setprio around MFMA cluster) + FIX: the K-loop is split back into two
//   phases with COMPILE-TIME accumulator binding. Round 6's single loop used
//   `(kt < 16) ? acX : acH` — a runtime-selected reference to a register
//   array, which forces the accumulators out of static register allocation
//   (rule #20: runtime-indexed register arrays -> scratch). That poisoned the
//   MFMA loop and regressed 522 -> 597 us.
//
// Layouts (unchanged):
//  xb[t][nb(64)][kt(16)][g(4)][row(64)][8] bf16 granules (16B).
//  Bt[cc(24)][kt(32)][g(4)][col(64)][8]    (cc = 64 gemm-cols).
//  h ping-pong: same granule layout as xb per nb.

typedef unsigned short u16;
typedef __attribute__((ext_vector_type(8))) short short8;
typedef __attribute__((ext_vector_type(8))) u16 u16x8;
typedef __attribute__((ext_vector_type(4))) float floatx4;

#define MFMA16(a, b, c) __builtin_amdgcn_mfma_f32_16x16x32_bf16((a), (b), (c), 0, 0, 0)

__device__ __forceinline__ u16 f32_to_bf16(float f) {
  union { float f; unsigned int u; } c; c.f = f;
  unsigned int u = c.u + 0x7FFFu + ((c.u >> 16) & 1u);  // RNE
  return (u16)(u >> 16);
}
__device__ __forceinline__ float bf16_to_f32(u16 v) {
  union { unsigned int u; float f; } c; c.u = ((unsigned int)v) << 16;
  return c.f;
}
__device__ __forceinline__ float sigmoidf_(float x) {
  return 1.0f / (1.0f + __expf(-x));
}
__device__ __forceinline__ void gload_lds16(const void* g, void* l) {
  __builtin_amdgcn_global_load_lds(
      (const __attribute__((address_space(1))) unsigned int*)g,
      (__attribute__((address_space(3))) unsigned int*)l, 16, 0, 0);
}

// ---------------------------------------------------------------------------
// pack_x: coalesced. Block = one (t, nb): 64 rows x 512 c.
// Phase A: read x rows coalesced (f32x8/thread), convert, store granules into
// LDS at XOR-swizzled column; Phase B: write granules [kt][g][row][8] coalesced.
// ---------------------------------------------------------------------------
__global__ __launch_bounds__(256)
void pack_x(const float* __restrict__ x, u16* __restrict__ xb) {
  __shared__ u16 sm[64 * 512];              // 64KB
  const int t = blockIdx.x >> 6;
  const int nb = blockIdx.x & 63;
  const int tid = threadIdx.x;
#pragma unroll
  for (int it = 0; it < 16; ++it) {
    int idx = it * 256 + tid;
    int row = idx >> 6, ch = idx & 63;      // row 0..63, ch = 8-float chunk
    int xrow = (nb * 2 + (row >> 5)) * 512 + t * 32 + (row & 31);
    const float* src = x + (size_t)xrow * 512 + ch * 8;
    floatx4 va = *(const floatx4*)src;
    floatx4 vb = *(const floatx4*)(src + 4);
    u16x8 pk;
    pk[0] = f32_to_bf16(va[0]); pk[1] = f32_to_bf16(va[1]);
    pk[2] = f32_to_bf16(va[2]); pk[3] = f32_to_bf16(va[3]);
    pk[4] = f32_to_bf16(vb[0]); pk[5] = f32_to_bf16(vb[1]);
    pk[6] = f32_to_bf16(vb[2]); pk[7] = f32_to_bf16(vb[3]);
    *(u16x8*)&sm[row * 512 + (ch ^ (row & 7)) * 8] = pk;
  }
  __syncthreads();
  u16* dst = xb + (size_t)blockIdx.x * 32768;   // blockIdx = t*64+nb = layout order
#pragma unroll
  for (int it = 0; it < 16; ++it) {
    int idx = it * 256 + tid;
    int row = idx & 63, g = (idx >> 6) & 3, kt = idx >> 8;
    int ch = kt * 4 + g;
    u16x8 vv = *(const u16x8*)&sm[row * 512 + (ch ^ (row & 7)) * 8];
    *(u16x8*)(dst + (size_t)idx * 8) = vv;
  }
}

// ---------------------------------------------------------------------------
// pack_Bt: [W;U] -> Bt bf16 [cc(24)][kt(32)][g(4)][col(64)][8]
// ---------------------------------------------------------------------------
__global__ void pack_Bt(const float* __restrict__ W, const float* __restrict__ U,
                        u16* __restrict__ Bt) {
  size_t gid = (size_t)blockIdx.x * 256 + threadIdx.x;   // < 196608
  int col = (int)(gid & 63);
  int g   = (int)((gid >> 6) & 3);
  int kt  = (int)((gid >> 8) & 31);
  int cc  = (int)(gid >> 13);
  int c = cc * 64 + col;
  int k0 = kt * 32 + g * 8;
  u16x8 pk;
#pragma unroll
  for (int j = 0; j < 8; ++j) {
    int k = k0 + j;
    float v = (k < 512) ? W[(size_t)k * 1536 + c] : U[(size_t)(k - 512) * 1536 + c];
    pk[j] = f32_to_bf16(v);
  }
  *(u16x8*)(Bt + gid * 8) = pk;
}

// ---------------------------------------------------------------------------
// gru_step: one GRU timestep.
// Grid 512 linear, XCD-swizzled: nb = (idx>>6)*8 + (idx&7), hb = (idx>>3)&7
// (all 8 hb-blocks of an nb land on one XCD; per-XCD set = 1MB A/h + 3MB B).
// Block tile 64n x 192c; 4 waves (wy,wx); wave = 32n x (3 gates x 32 h-cols).
// LDS: 4 x 16KB ring (A 4KB [g4][row64][16B] + B 3 x 4KB [g4][col64][16B]).
// K-loop: counted-vmcnt pipeline, 3 stages in flight, one s_barrier per kt,
// split into two phases with compile-time accumulator binding.
// ---------------------------------------------------------------------------
__global__ __launch_bounds__(256)
void gru_step(const u16* __restrict__ xb, const u16* __restrict__ Bt,
              const float* __restrict__ bias,
              const u16* __restrict__ h_in, u16* __restrict__ h_out,
              float* __restrict__ out, int t, int first, int last) {
  __shared__ alignas(16) char sm[65536];    // 4 x 16KB ring -> 2 blocks/CU
  const int tid = threadIdx.x;
  const int idx = blockIdx.x;
  const int nb = ((idx >> 6) << 3) | (idx & 7);   // 0..63
  const int hb = (idx >> 3) & 7;                  // 0..7
  // WAVE-UNIFORM wave id: forces SGPR so global_load_lds LDS destinations are
  // provably uniform (no compiler waterfall around each load).
  const int w = __builtin_amdgcn_readfirstlane(tid >> 6);
  const int lane = tid & 63;
  const int wy = w >> 1, wx = w & 1;              // scalar
  const int q = lane >> 4, lc = lane & 15;

  const u16* xbB = xb + (size_t)(t * 64 + nb) * 32768;
  const u16* htB = h_in + (size_t)nb * 32768;
  const int cs0 = hb, cs1 = 8 + hb, cs2 = 16 + hb;   // z / r / h-gate col-chunks

  floatx4 acZ[2][2] = {{{0.f,0.f,0.f,0.f},{0.f,0.f,0.f,0.f}},{{0.f,0.f,0.f,0.f},{0.f,0.f,0.f,0.f}}};
  floatx4 acR[2][2] = {{{0.f,0.f,0.f,0.f},{0.f,0.f,0.f,0.f}},{{0.f,0.f,0.f,0.f},{0.f,0.f,0.f,0.f}}};
  floatx4 acX[2][2] = {{{0.f,0.f,0.f,0.f},{0.f,0.f,0.f,0.f}},{{0.f,0.f,0.f,0.f},{0.f,0.f,0.f,0.f}}};
  floatx4 acH[2][2] = {{{0.f,0.f,0.f,0.f},{0.f,0.f,0.f,0.f}},{{0.f,0.f,0.f,0.f},{0.f,0.f,0.f,0.f}}};

  const int wo = w * 1024;   // SGPR: per-wave byte slot within each 4KB panel

  // Stage K-chunk kt (A 4KB + 3 gate-B 4KB) into ring slot bsel. 4 glds16/wave.
  auto stage = [&](int kt, int bsel) {
    char* lds = sm + bsel * 16384;            // bsel scalar -> uniform base
    const char* aS = (const char*)((kt < 16) ? (xbB + (size_t)kt * 2048)
                                             : (htB + (size_t)(kt - 16) * 2048));
    gload_lds16(aS + wo + lane * 16, lds + wo);
    gload_lds16((const char*)(Bt + (size_t)(cs0 * 32 + kt) * 2048) + wo + lane * 16,
                lds + 4096 + wo);
    gload_lds16((const char*)(Bt + (size_t)(cs1 * 32 + kt) * 2048) + wo + lane * 16,
                lds + 8192 + wo);
    gload_lds16((const char*)(Bt + (size_t)(cs2 * 32 + kt) * 2048) + wo + lane * 16,
                lds + 12288 + wo);
  };

  // Compute one K-chunk from ring slot bsel; third-gate acc is acX (x@W) / acH.
  // Every call site binds acT at COMPILE TIME (no runtime select).
  auto compute = [&](int bsel, floatx4 (&acT)[2][2]) {
    const char* lds = sm + bsel * 16384;
    short8 a0 = *(const short8*)(lds + (q * 64 + wy * 32 + lc) * 16);
    short8 a1 = *(const short8*)(lds + (q * 64 + wy * 32 + 16 + lc) * 16);
#pragma unroll
    for (int ci = 0; ci < 2; ++ci) {
      int co = (q * 64 + wx * 32 + ci * 16 + lc) * 16;
      short8 bz = *(const short8*)(lds + 4096 + co);
      short8 br = *(const short8*)(lds + 8192 + co);
      short8 bh = *(const short8*)(lds + 12288 + co);
      acZ[0][ci] = MFMA16(a0, bz, acZ[0][ci]);
      acZ[1][ci] = MFMA16(a1, bz, acZ[1][ci]);
      acR[0][ci] = MFMA16(a0, br, acR[0][ci]);
      acR[1][ci] = MFMA16(a1, br, acR[1][ci]);
      acT[0][ci] = MFMA16(a0, bh, acT[0][ci]);
      acT[1][ci] = MFMA16(a1, bh, acT[1][ci]);
    }
  };

  // ---- Pipelined K-loop: 3 stages in flight, counted vmcnt, 1 barrier/kt.
  // vmcnt invariant at iter kt: newest 8 outstanding loads belong to stages
  // kt+1,kt+2 -> vmcnt(8) guarantees own stage(kt) landed (in-order retire);
  // the s_barrier then publishes all waves' stage(kt). stage(kt+3) overwrites
  // buf[(kt-1)&3], which every wave finished reading before this barrier
  // (all its ds_read results are consumed by MFMAs in compute(kt-1)).
  stage(0, 0);
  stage(1, 1);
  stage(2, 2);
  if (first) {
    // Phase 0 only: kt = 0..15, acc acX. Stages stop at 15.
    for (int kt = 0; kt < 14; ++kt) {
      asm volatile("s_waitcnt vmcnt(8)" ::: "memory");
      __builtin_amdgcn_s_barrier();
      if (kt < 13) stage(kt + 3, (kt + 3) & 3);
      __builtin_amdgcn_s_setprio(1);
      compute(kt & 3, acX);
      __builtin_amdgcn_s_setprio(0);
    }
    asm volatile("s_waitcnt vmcnt(4)" ::: "memory");
    __builtin_amdgcn_s_barrier();
    __builtin_amdgcn_s_setprio(1);
    compute(2, acX);                         // kt=14
    __builtin_amdgcn_s_setprio(0);
    asm volatile("s_waitcnt vmcnt(0)" ::: "memory");
    __builtin_amdgcn_s_barrier();
    __builtin_amdgcn_s_setprio(1);
    compute(3, acX);                         // kt=15
    __builtin_amdgcn_s_setprio(0);
  } else {
    // Phase 0: kt = 0..15, acc acX; stages run ahead into phase 1 chunks.
    for (int kt = 0; kt < 16; ++kt) {
      asm volatile("s_waitcnt vmcnt(8)" ::: "memory");
      __builtin_amdgcn_s_barrier();
      stage(kt + 3, (kt + 3) & 3);           // 3..18, always valid
      __builtin_amdgcn_s_setprio(1);
      compute(kt & 3, acX);
      __builtin_amdgcn_s_setprio(0);
    }
    // Phase 1: kt = 16..31, acc acH. Stages stop at 31.
    for (int kt = 16; kt < 30; ++kt) {
      asm volatile("s_waitcnt vmcnt(8)" ::: "memory");
      __builtin_amdgcn_s_barrier();
      if (kt < 29) stage(kt + 3, (kt + 3) & 3);
      __builtin_amdgcn_s_setprio(1);
      compute(kt & 3, acH);
      __builtin_amdgcn_s_setprio(0);
    }
    asm volatile("s_waitcnt vmcnt(4)" ::: "memory");
    __builtin_amdgcn_s_barrier();
    __builtin_amdgcn_s_setprio(1);
    compute(2, acH);                         // kt=30
    __builtin_amdgcn_s_setprio(0);
    asm volatile("s_waitcnt vmcnt(0)" ::: "memory");
    __builtin_amdgcn_s_barrier();
    __builtin_amdgcn_s_setprio(1);
    compute(3, acH);                         // kt=31
    __builtin_amdgcn_s_setprio(0);
  }

  // ---- Epilogue. C/D layout: col = lane&15, row = quad*4 + reg ----
  __syncthreads();   // all compute done before Ct reuse of sm
  const float* b0 = bias;
  const float* b1 = bias + 1536;
  u16* Ct = (u16*)sm;    // 64 rows x 72 u16 (9KB)
#pragma unroll
  for (int ci = 0; ci < 2; ++ci) {
    const int hcl = wx * 32 + ci * 16 + lc;    // 0..63
    const int hg = hb * 64 + hcl;              // 0..511
    const float bz = b0[hg] + b1[hg];
    const float br = b0[512 + hg] + b1[512 + hg];
    const float b0h = b0[1024 + hg];
    const float b1h = b1[1024 + hg];
    const int ktg = hg >> 5;
    const int gg = (hg >> 3) & 3;
    const size_t hbase = (((size_t)nb * 16 + ktg) * 4 + gg) * 64;
#pragma unroll
    for (int mi = 0; mi < 2; ++mi) {
#pragma unroll
      for (int reg = 0; reg < 4; ++reg) {
        const int nl = wy * 32 + mi * 16 + q * 4 + reg;   // 0..63
        const int n = nb * 64 + nl;
        float z = sigmoidf_(acZ[mi][ci][reg] + bz);
        float r = sigmoidf_(acR[mi][ci][reg] + br);
        float hh = acX[mi][ci][reg] + b0h + r * (acH[mi][ci][reg] + b1h);
        hh = fmaxf(hh, 0.0f);
        float hp = 0.0f;
        if (!first) hp = bf16_to_f32(h_in[(hbase + nl) * 8 + (hg & 7)]);
        float v = z * hp + (1.0f - z) * hh;
        if (last) out[(size_t)n * 512 + hg] = v;
        else      Ct[nl * 72 + hcl] = f32_to_bf16(v);
      }
    }
  }
  if (!last) {
    __syncthreads();
    // Re-emit h in granule layout: 512 granules (row64 x g4 x ktl2), 2/thread.
#pragma unroll
    for (int i = 0; i < 2; ++i) {
      int e = i * 256 + tid;
      int row = e & 63;
      int g = (e >> 6) & 3;
      int ktl = e >> 8;                         // 0..1
      u16x8 vv = *(const u16x8*)(Ct + row * 72 + ktl * 32 + g * 8);
      *(u16x8*)(h_out + ((((size_t)nb * 16 + (hb * 2 + ktl)) * 4 + g) * 64 + row) * 8) = vv;
    }
  }
}

// ---------------------------------------------------------------------------
extern "C" void kernel_launch(void* const* d_in, const int* in_sizes, int n_in,
                              void* d_out, int out_size, void* d_ws, size_t ws_size,
                              hipStream_t stream) {
  const float* x = (const float*)d_in[0];    // (128,512,512)
  const float* W = (const float*)d_in[1];    // (512,1536)
  const float* U = (const float*)d_in[2];    // (512,1536)
  const float* bias = (const float*)d_in[3]; // (2,1536)
  float* out = (float*)d_out;                // (128,16384)

  u16* xb = (u16*)d_ws;                      // 16*64*32768 u16 = 64 MB
  u16* Bt = xb + (size_t)16 * 64 * 32768;    // 3 MB
  u16* h0 = Bt + (size_t)1536 * 1024;        // 4 MB
  u16* h1 = h0 + (size_t)4096 * 512;         // 4 MB

  pack_x<<<1024, 256, 0, stream>>>(x, xb);
  pack_Bt<<<768, 256, 0, stream>>>(W, U, Bt);

  for (int t = 0; t < 16; ++t) {
    const u16* hin = (t & 1) ? h1 : h0;      // t=0 never reads h
    u16* hout = (t & 1) ? h0 : h1;
    gru_step<<<512, 256, 0, stream>>>(
        xb, Bt, bias, hin, hout, out, t, (t == 0) ? 1 : 0, (t == 15) ? 1 : 0);
  }
}